// Round 1
// baseline (60.440 us; speedup 1.0000x reference)
//
#include <hip/hip_runtime.h>
#include <stdint.h>

// Soft-logic FP32 adder circuit, emulated exactly in integer arithmetic on the
// packed 32-bit word. Bit p in memory (p=0 sign, 1..8 exp MSB..LSB, 9..31 mant
// MSB..LSB) maps to IEEE bit (31-p) of the packed word.
__device__ __forceinline__ uint32_t soft_fp32_add(uint32_t aw, uint32_t bw) {
    const uint32_t M28 = 0x0FFFFFFFu;
    uint32_t sa = aw >> 31, sb = bw >> 31;
    uint32_t ea = (aw >> 23) & 0xFFu, eb = (bw >> 23) & 0xFFu;
    uint32_t ma = aw & 0x7FFFFFu,     mb = bw & 0x7FFFFFu;
    uint32_t ha = (ea != 0u) ? 1u : 0u, hb = (eb != 0u) ? 1u : 0u;
    uint32_t eaf = ha ? ea : 1u;                 // effective exponent (subnormal -> 1)
    uint32_t ebf = hb ? eb : 1u;
    uint32_t mA = (ha << 27) | (ma << 4);        // 28-bit: hidden | mant | 4 guard zeros
    uint32_t mB = (hb << 27) | (mb << 4);
    // magnitude compare, lexicographic on (e_eff, hidden|mant)
    uint32_t keyA = (eaf << 24) | (ha << 23) | ma;
    uint32_t keyB = (ebf << 24) | (hb << 23) | mb;
    uint32_t age  = (keyA >= keyB) ? 1u : 0u;    // a_ge_b
    uint32_t abeq = (keyA == keyB) ? 1u : 0u;    // |A| == |B|
    uint32_t ediff = age ? (eaf - ebf) : (ebf - eaf);   // nonnegative by selection
    uint32_t big = (ediff >= 24u) ? 1u : 0u;     // is_big_diff (bits>=32 or (b4&b3))
    uint32_t sh  = ediff & 31u;                  // shift_amt = low 5 bits
    uint32_t emax = age ? eaf : ebf;
    uint32_t ml   = age ? mA : mB;
    uint32_t msu  = age ? mB : mA;               // m_small unshifted
    uint32_t ms     = msu >> sh;
    uint32_t sticky = ((msu & ((1u << sh) - 1u)) != 0u) ? 1u : 0u;
    if (big) { ms = 0u; sticky = (msu != 0u) ? 1u : 0u; }
    uint32_t dsgn   = sa ^ sb;                   // is_diff_sign
    uint32_t cancel = dsgn & abeq;               // exact_cancel
    uint32_t sl     = age ? sa : sb;             // s_large
    uint32_t sum    = ml + ms;                   // 29-bit
    uint32_t scarry = sum >> 28;
    uint32_t sres   = sum & M28;
    uint32_t diff   = (ml - ms) & M28;
    uint32_t dfin   = (dsgn & sticky) ? ((diff - 1u) & M28) : diff;  // need_sub_one
    uint32_t mant   = dsgn ? dfin : sres;        // mant_res
    uint32_t rc     = dsgn ? 0u : scarry;        // result_carry
    uint32_t lzc    = mant ? (uint32_t)(__clz((int)mant) - 4) : 28u; // lzd28
    uint32_t undf   = (lzc >= emax) ? 1u : 0u;   // is_underflow (lzc8 >= e_max)
    uint32_t norm   = (mant << lzc) & M28;       // barrel_left
    uint32_t e_aft  = (emax - lzc) & 0xFFu;      // 8-bit wrap
    uint32_t e_p1   = (emax + 1u) & 0xFFu;
    uint32_t e_nrm  = undf ? 0u : e_aft;
    uint32_t fe     = rc ? e_p1 : e_nrm;         // final_e_pre
    uint32_t m_ovf  = mant >> 5;                 // bits 0..22  (also == m_subnorm)
    uint32_t r_ovf  = (mant >> 4) & 1u;          // bit 23
    uint32_t st_ovf = ((mant & 0xFu) != 0u) ? 1u : 0u;   // bits 24..27
    uint32_t m_nrm  = (norm >> 4) & 0x7FFFFFu;   // bits 1..23
    uint32_t r_nrm  = (norm >> 3) & 1u;          // bit 24
    uint32_t st_nrm = ((norm & 7u) != 0u) ? 1u : 0u;     // bits 25..27
    uint32_t m_pre  = rc ? m_ovf : m_nrm;
    uint32_t r_pre  = rc ? r_ovf : r_nrm;
    uint32_t st_pre = (rc ? st_ovf : st_nrm) | sticky;
    uint32_t m_sel  = undf ? m_ovf : m_pre;      // underflow -> truncated subnormal
    uint32_t Lb     = m_sel & 1u;
    uint32_t dor    = r_pre & (st_pre | Lb) & (undf ^ 1u);   // do_round (RNE)
    uint32_t mr     = m_sel + dor;               // 24-bit
    uint32_t rcar   = mr >> 23;                  // round_carry
    uint32_t m_fin  = mr & 0x7FFFFFu;            // AND(NOT(rcar), rounded) == this
    uint32_t ce     = (fe + rcar) & 0xFFu;       // computed_e
    uint32_t os = cancel ? 0u : sl;
    uint32_t oe = cancel ? 0u : ce;
    uint32_t om = cancel ? 0u : m_fin;
    uint32_t ea1 = (ea == 0xFFu) ? 1u : 0u, eb1 = (eb == 0xFFu) ? 1u : 0u;
    uint32_t manz = (ma != 0u) ? 1u : 0u, mbnz = (mb != 0u) ? 1u : 0u;
    uint32_t anynan = (ea1 & manz) | (eb1 & mbnz);
    uint32_t ainf = ea1 & (manz ^ 1u);
    uint32_t binf = eb1 & (mbnz ^ 1u);
    uint32_t anyinf = ainf | binf;
    uint32_t isnan  = anynan | (dsgn & ainf & binf);
    uint32_t ovf    = (ce == 0xFFu) ? 1u : 0u;   // on computed_e, pre-cancel
    uint32_t out = (os << 31) | (oe << 23) | om;
    if (anyinf | ovf) out = (sl << 31) | (0xFFu << 23);   // inf_res
    if (isnan)        out = (0xFFu << 23) | 0x7FFFFFu;    // nan_res (sign=0)
    return out;
}

// Wave-cooperative: each 64-lane wave owns 64 rows (2048 floats per input).
// Pack via __ballot (coalesced 4B/lane loads), circuit per lane, unpack via
// __shfl (coalesced 4B/lane stores).
__global__ __launch_bounds__(256) void SpikeFP32Adder_kernel(
    const float* __restrict__ A, const float* __restrict__ B,
    float* __restrict__ O, int nrows)
{
    const int lane = threadIdx.x & 63;
    const long long wave = (long long)((blockIdx.x * (long long)blockDim.x + threadIdx.x) >> 6);
    const long long rowBase = wave * 64;
    if (rowBase >= nrows) return;              // wave-uniform guard

    const size_t base = (size_t)rowBase * 32;  // float index of this wave's chunk
    const size_t total = (size_t)nrows * 32;
    const bool full = (rowBase + 64 <= (long long)nrows);   // wave-uniform

    uint32_t aw = 0u, bw = 0u;
    #pragma unroll
    for (int i = 0; i < 32; ++i) {
        size_t idx = base + (size_t)i * 64 + lane;
        float va = (full || idx < total) ? A[idx] : 0.0f;
        unsigned long long mk = __ballot(va != 0.0f);
        uint32_t half = (lane & 1) ? (uint32_t)(mk >> 32) : (uint32_t)mk;
        if ((lane >> 1) == i) aw = half;
    }
    #pragma unroll
    for (int i = 0; i < 32; ++i) {
        size_t idx = base + (size_t)i * 64 + lane;
        float vb = (full || idx < total) ? B[idx] : 0.0f;
        unsigned long long mk = __ballot(vb != 0.0f);
        uint32_t half = (lane & 1) ? (uint32_t)(mk >> 32) : (uint32_t)mk;
        if ((lane >> 1) == i) bw = half;
    }
    aw = __brev(aw);   // memory bit p -> IEEE bit (31-p)
    bw = __brev(bw);

    uint32_t outw = soft_fp32_add(aw, bw);

    const uint32_t shp = 31u - (uint32_t)(lane & 31);
    #pragma unroll
    for (int i = 0; i < 32; ++i) {
        uint32_t w = (uint32_t)__shfl((int)outw, 2 * i + (lane >> 5));
        size_t idx = base + (size_t)i * 64 + lane;
        if (full || idx < total)
            O[idx] = (float)((w >> shp) & 1u);
    }
}

extern "C" void kernel_launch(void* const* d_in, const int* in_sizes, int n_in,
                              void* d_out, int out_size, void* d_ws, size_t ws_size,
                              hipStream_t stream) {
    const float* A = (const float*)d_in[0];
    const float* B = (const float*)d_in[1];
    float* O = (float*)d_out;
    int nrows = in_sizes[0] / 32;              // 524288
    long long waves = ((long long)nrows + 63) / 64;
    int threads = 256;
    long long blocks = (waves * 64 + threads - 1) / threads;
    SpikeFP32Adder_kernel<<<dim3((unsigned)blocks), dim3(threads), 0, stream>>>(A, B, O, nrows);
}